// Round 1
// baseline (538.222 us; speedup 1.0000x reference)
//
#include <hip/hip_runtime.h>
#include <math.h>

#define CCH   128        // C
#define C2    64         // C/2
#define C2X   256        // 2C
#define CR    8          // C/16
#define HW    16384
#define NB    16
#define EPSB  1e-5f

// workspace layout (float offsets)
#define WS_POOLED 0          // 4096
#define WS_WCH    4096       // 2048
#define WS_AVGS   6144       // 2048
#define WS_MAXB   8192       // 2048 (uint bits)
#define WS_CA     10240      // 2048
#define WS_BC     12288      // 128
#define WS_WV     16384      // 131072 floats worth (262144 bf16)  [n][o][c]
#define WS_WI     147456     // 131072
#define WS_SPMEAN 278528     // 262144
#define WS_SPMAX  540672     // 262144
#define WS_SA     802816     // 262144  (end: 1064960 floats = 4.06 MB)

typedef short short8 __attribute__((ext_vector_type(8)));
typedef float floatx4 __attribute__((ext_vector_type(4)));
typedef unsigned short ushort_t;
typedef unsigned int uint_t;

__device__ __forceinline__ float sigmoidf_(float x) {
    return 1.0f / (1.0f + __expf(-x));
}

// fp32 -> bf16 with round-to-nearest-even
__device__ __forceinline__ uint_t f2bf(float f) {
    uint_t u = __float_as_uint(f);
    return (u + 0x7FFFu + ((u >> 16) & 1u)) >> 16;
}
__device__ __forceinline__ uint_t pack2bf(float a, float b) {
    return f2bf(a) | (f2bf(b) << 16);
}

// ---------------------------------------------------------------- global mean pool of [f_vi, f_ir]
// ILP fix: 16-wide unroll, 4 independent accumulators -> multiple loads in flight
// (previous version: VGPR=8, one float4 outstanding, latency-serialized at 1.3 TB/s)
__global__ void k_pool(const float* __restrict__ fvi, const float* __restrict__ fir,
                       float* __restrict__ pooled) {
    int b  = blockIdx.x;            // n*256 + ch
    int n  = b >> 8;
    int ch = b & 255;
    const float* src = (ch < CCH) ? (fvi + ((size_t)n * CCH + ch) * HW)
                                  : (fir + ((size_t)n * CCH + (ch - CCH)) * HW);
    const float4* s4 = (const float4*)src;
    float s0 = 0.f, s1 = 0.f, s2 = 0.f, s3 = 0.f;
    #pragma unroll
    for (int it = 0; it < 4; ++it) {
        float4 v0 = s4[threadIdx.x + (it * 4 + 0) * 256];
        float4 v1 = s4[threadIdx.x + (it * 4 + 1) * 256];
        float4 v2 = s4[threadIdx.x + (it * 4 + 2) * 256];
        float4 v3 = s4[threadIdx.x + (it * 4 + 3) * 256];
        s0 += (v0.x + v0.y) + (v0.z + v0.w);
        s1 += (v1.x + v1.y) + (v1.z + v1.w);
        s2 += (v2.x + v2.y) + (v2.z + v2.w);
        s3 += (v3.x + v3.y) + (v3.z + v3.w);
    }
    float sum = (s0 + s1) + (s2 + s3);
    #pragma unroll
    for (int off = 32; off > 0; off >>= 1) sum += __shfl_down(sum, off, 64);
    __shared__ float r[4];
    if ((threadIdx.x & 63) == 0) r[threadIdx.x >> 6] = sum;
    __syncthreads();
    if (threadIdx.x == 0)
        pooled[b] = (r[0] + r[1] + r[2] + r[3]) * (1.0f / HW);
}

// ---------------------------------------------------------------- channel-attention MLP -> wch
__global__ void k_wch(const float* __restrict__ pooled,
                      const float* __restrict__ ca1_w, const float* __restrict__ ca1_b,
                      const float* __restrict__ ag, const float* __restrict__ ab,
                      const float* __restrict__ am, const float* __restrict__ av,
                      const float* __restrict__ ca2_w, const float* __restrict__ ca2_b,
                      const float* __restrict__ bg, const float* __restrict__ bb,
                      const float* __restrict__ bm, const float* __restrict__ bv,
                      float* __restrict__ wch) {
    int n = blockIdx.x;
    int t = threadIdx.x;            // 128 threads
    __shared__ float h[C2];
    if (t < C2) {
        float acc = ca1_b[t];
        const float* w = ca1_w + t * C2X;
        const float* p = pooled + n * C2X;
        for (int k = 0; k < C2X; k++) acc += w[k] * p[k];
        float s = ag[t] * rsqrtf(av[t] + EPSB);
        acc = (acc - am[t]) * s + ab[t];
        h[t] = fmaxf(acc, 0.f);
    }
    __syncthreads();
    float acc = ca2_b[t];
    const float* w = ca2_w + t * C2;
    for (int j = 0; j < C2; j++) acc += w[j] * h[j];
    float s = bg[t] * rsqrtf(bv[t] + EPSB);
    acc = (acc - bm[t]) * s + bb[t];
    wch[n * CCH + t] = sigmoidf_(acc);
}

// ---------------------------------------------------------------- per-batch effective bf16 conv weights
// Wv[n][o][c] = bf16( A[o]*(W[o][c] + u[n][c]*W[o][c+C]) ), Wi = swap.  Also folds:
// zeroing of avgsum/maxbits (blocks 0..15) and the bn_c-folded bias (block 16).
__global__ void k_mkweights(const float* __restrict__ wch, const float* __restrict__ conv1_w,
                            const float* __restrict__ cg, const float* __restrict__ cb,
                            const float* __restrict__ cm, const float* __restrict__ cv,
                            const float* __restrict__ conv1_b,
                            ushort_t* __restrict__ Wv, ushort_t* __restrict__ Wi,
                            float* __restrict__ Bc, float* __restrict__ zeroreg) {
    int b = blockIdx.x;             // n*128 + o
    int t = threadIdx.x;            // 128 = c
    if (b < 16) { zeroreg[b * 256 + t] = 0.f; zeroreg[b * 256 + 128 + t] = 0.f; }
    if (b == 16) {
        float A = cg[t] * rsqrtf(cv[t] + EPSB);
        Bc[t] = A * (conv1_b[t] - cm[t]) + cb[t];
    }
    int n = b >> 7, o = b & 127;
    float A  = cg[o] * rsqrtf(cv[o] + EPSB);
    float u  = wch[n * CCH + t];
    float w0 = conv1_w[o * C2X + t];
    float w1 = conv1_w[o * C2X + t + CCH];
    Wv[(size_t)b * CCH + t] = (ushort_t)f2bf(A * (w0 + u * w1));
    Wi[(size_t)b * CCH + t] = (ushort_t)f2bf(A * (w1 + u * w0));
}

// ---------------------------------------------------------------- fused conv1x1+bn+relu + reductions (MFMA)
// grid: 16 n x 128 p-tiles; block: 256 threads = 4 waves
// Restructured as a single K=256 GEMM (vi c0..128 then ir c0..128), 8 K-steps of 32:
//   - only 2 LDS tiles live (32 KB vs 40 KB) -> more blocks/CU
//   - 128 B LDS rows + XOR chunk swizzle (slot = chunk ^ (row&7)):
//       b128 fragment reads are 2-way (free); old 80 B rows were 8-way conflicted
//   - X staging uses float4 global loads (4x fewer load instructions)
#define XR 64   // LDS row stride in bf16 elems = 128 B (swizzled, half-occupied by data)
__global__ __launch_bounds__(256)
void k_conv_reduce(const float* __restrict__ fvi, const float* __restrict__ fir,
                   const ushort_t* __restrict__ Wv, const ushort_t* __restrict__ Wi,
                   const float* __restrict__ Bc,
                   float* __restrict__ avgsum, uint_t* __restrict__ maxbits,
                   float* __restrict__ spmean, float* __restrict__ spmax) {
    int n  = blockIdx.x >> 7;
    int pt = blockIdx.x & 127;
    int p0 = pt * 128;

    __shared__ __align__(16) ushort_t sW[128 * XR];   // W tile: [o][c-chunk swizzled]
    __shared__ __align__(16) ushort_t sX[128 * XR];   // X tile: [p][c-chunk swizzled]

    int tid  = threadIdx.x;
    int wave = tid >> 6;
    int lane = tid & 63;
    int q    = lane >> 4;       // 0..3
    int ln   = lane & 15;

    floatx4 acc[2][8];
    #pragma unroll
    for (int a = 0; a < 2; a++)
        #pragma unroll
        for (int b = 0; b < 8; b++) acc[a][b] = (floatx4){0.f, 0.f, 0.f, 0.f};

    const float* pv = fvi + (size_t)n * CCH * HW + p0;
    const float* pi = fir + (size_t)n * CCH * HW + p0;
    const ushort_t* wvb = Wv + (size_t)n * CCH * CCH;
    const ushort_t* wib = Wi + (size_t)n * CCH * CCH;

    // staging coordinates (fixed per thread)
    int wo  = tid >> 2, wc = tid & 3;       // W: row o (+64*it), 16B chunk wc
    int xpq = tid & 15, xcp = tid >> 4;     // X: p-quad (+16*it), channel-pair xcp
    int xch = xcp >> 2, xdw = xcp & 3;      // chunk / dword-in-chunk of xcp

    for (int ks = 0; ks < 8; ++ks) {
        const ushort_t* wsrc = (ks < 4) ? wvb : wib;
        const float*    xsrc = (ks < 4) ? pv  : pi;
        int c0 = (ks & 3) * 32;

        __syncthreads();   // previous compute done before overwrite
        // --- stage W: 128 o x 32 c bf16; b128 writes, conflict-free under swizzle
        #pragma unroll
        for (int it = 0; it < 2; ++it) {
            int o = it * 64 + wo;
            uint4 w4 = *(const uint4*)&wsrc[(size_t)o * CCH + c0 + wc * 8];
            *(uint4*)&sW[o * XR + ((wc ^ (o & 7)) << 3)] = w4;
        }
        // --- stage X: 32 c x 128 p fp32 -> bf16 pairs, float4 loads (coalesced 256 B runs)
        #pragma unroll
        for (int it = 0; it < 2; ++it) {
            int pq = (it << 4) | xpq;                 // 0..31 -> p = 4*pq..4*pq+3
            const float* sp = xsrc + (size_t)(c0 + 2 * xcp) * HW + 4 * pq;
            float4 f1 = *(const float4*)sp;           // channel c0+2*xcp
            float4 f2 = *(const float4*)(sp + HW);    // channel c0+2*xcp+1
            int r0 = 4 * pq;
            *(uint_t*)&sX[(r0 + 0) * XR + ((xch ^ ((r0 + 0) & 7)) << 3) + xdw * 2] = pack2bf(f1.x, f2.x);
            *(uint_t*)&sX[(r0 + 1) * XR + ((xch ^ ((r0 + 1) & 7)) << 3) + xdw * 2] = pack2bf(f1.y, f2.y);
            *(uint_t*)&sX[(r0 + 2) * XR + ((xch ^ ((r0 + 2) & 7)) << 3) + xdw * 2] = pack2bf(f1.z, f2.z);
            *(uint_t*)&sX[(r0 + 3) * XR + ((xch ^ ((r0 + 3) & 7)) << 3) + xdw * 2] = pack2bf(f1.w, f2.w);
        }
        __syncthreads();

        // --- frags + MFMA (swizzled reads, 2-way banks = free)
        short8 aW0, aW1;
        {
            int rA0 = wave * 32 + ln;
            int rA1 = rA0 + 16;
            aW0 = *(const short8*)&sW[rA0 * XR + ((q ^ (rA0 & 7)) << 3)];
            aW1 = *(const short8*)&sW[rA1 * XR + ((q ^ (rA1 & 7)) << 3)];
        }
        #pragma unroll
        for (int pj = 0; pj < 8; ++pj) {
            int rB = pj * 16 + ln;
            short8 bX = *(const short8*)&sX[rB * XR + ((q ^ (rB & 7)) << 3)];
            acc[0][pj] = __builtin_amdgcn_mfma_f32_16x16x32_bf16(aW0, bX, acc[0][pj], 0, 0, 0);
            acc[1][pj] = __builtin_amdgcn_mfma_f32_16x16x32_bf16(aW1, bX, acc[1][pj], 0, 0, 0);
        }
    }

    // --- epilogue: g = relu(acc + Bc[o]); C/D layout: col = ln (p), row = q*4+r (o within 16)
    float bc[2][4];
    #pragma unroll
    for (int ot = 0; ot < 2; ++ot)
        #pragma unroll
        for (int r = 0; r < 4; ++r)
            bc[ot][r] = Bc[wave * 32 + ot * 16 + q * 4 + r];

    float rs[2][4], rm[2][4], ps[8], pm[8];
    #pragma unroll
    for (int ot = 0; ot < 2; ++ot)
        #pragma unroll
        for (int r = 0; r < 4; ++r) { rs[ot][r] = 0.f; rm[ot][r] = 0.f; }
    #pragma unroll
    for (int pj = 0; pj < 8; ++pj) { ps[pj] = 0.f; pm[pj] = 0.f; }

    #pragma unroll
    for (int ot = 0; ot < 2; ++ot)
        #pragma unroll
        for (int pj = 0; pj < 8; ++pj) {
            floatx4 a = acc[ot][pj];
            #pragma unroll
            for (int r = 0; r < 4; ++r) {
                float g = fmaxf(a[r] + bc[ot][r], 0.f);
                rs[ot][r] += g;
                rm[ot][r] = fmaxf(rm[ot][r], g);
                ps[pj] += g;
                pm[pj] = fmaxf(pm[pj], g);
            }
        }

    // per-o: reduce over the 16 lanes of each quad (cols) -> atomics
    #pragma unroll
    for (int ot = 0; ot < 2; ++ot)
        #pragma unroll
        for (int r = 0; r < 4; ++r)
            #pragma unroll
            for (int off = 1; off < 16; off <<= 1) {
                rs[ot][r] += __shfl_xor(rs[ot][r], off, 64);
                rm[ot][r] = fmaxf(rm[ot][r], __shfl_xor(rm[ot][r], off, 64));
            }
    if (ln == 0) {
        #pragma unroll
        for (int ot = 0; ot < 2; ++ot)
            #pragma unroll
            for (int r = 0; r < 4; ++r) {
                int o = wave * 32 + ot * 16 + q * 4 + r;
                atomicAdd(&avgsum[n * CCH + o], rs[ot][r]);
                atomicMax(&maxbits[n * CCH + o], __float_as_uint(rm[ot][r]));  // g >= 0
            }
    }

    // per-p: reduce over q (rows within wave), then across waves via LDS
    #pragma unroll
    for (int pj = 0; pj < 8; ++pj) {
        #pragma unroll
        for (int off = 16; off < 64; off <<= 1) {
            ps[pj] += __shfl_xor(ps[pj], off, 64);
            pm[pj] = fmaxf(pm[pj], __shfl_xor(pm[pj], off, 64));
        }
    }
    __syncthreads();                       // done reading staged tiles
    float* redS = (float*)sW;              // [4 waves][128 p]
    float* redM = (float*)sX;
    if (lane < 16) {
        #pragma unroll
        for (int pj = 0; pj < 8; ++pj) {
            redS[wave * 128 + pj * 16 + ln] = ps[pj];
            redM[wave * 128 + pj * 16 + ln] = pm[pj];
        }
    }
    __syncthreads();
    if (tid < 128) {
        float s = 0.f, m = 0.f;
        #pragma unroll
        for (int w = 0; w < 4; ++w) {
            s += redS[w * 128 + tid];
            m = fmaxf(m, redM[w * 128 + tid]);
        }
        spmean[(size_t)n * HW + p0 + tid] = s * (1.0f / CCH);
        spmax [(size_t)n * HW + p0 + tid] = m;
    }
}

// ---------------------------------------------------------------- channel attention (CBAM-style MLP)
__global__ void k_ca(const float* __restrict__ avgsum, const uint_t* __restrict__ maxbits,
                     const float* __restrict__ w1, const float* __restrict__ w2,
                     float* __restrict__ ca) {
    int n = blockIdx.x;
    int t = threadIdx.x;            // 128
    __shared__ float tsum[CR];
    if (t < CR) {
        float a = 0.f, m = 0.f;
        const float* w = w1 + t * CCH;
        for (int c = 0; c < CCH; c++) {
            a += w[c] * (avgsum[n * CCH + c] * (1.0f / HW));
            m += w[c] * __uint_as_float(maxbits[n * CCH + c]);
        }
        tsum[t] = fmaxf(a, 0.f) + fmaxf(m, 0.f);
    }
    __syncthreads();
    float s = 0.f;
    #pragma unroll
    for (int j = 0; j < CR; j++) s += w2[t * CR + j] * tsum[j];
    ca[n * CCH + t] = sigmoidf_(s);
}

// ---------------------------------------------------------------- 7x7 spatial-attention conv
// 256-thread blocks (4 waves), 2 rows per block, for better latency hiding
__global__ void k_sa(const float* __restrict__ spmean, const float* __restrict__ spmax,
                     const float* __restrict__ sw, float* __restrict__ sa) {
    int b = blockIdx.x;             // n*64 + yhalf
    int n = b >> 6;
    int y = ((b & 63) << 1) | (threadIdx.x >> 7);
    int x = threadIdx.x & 127;
    float acc = 0.f;
    for (int dy = -3; dy <= 3; dy++) {
        int yy = y + dy;
        if ((unsigned)yy >= 128u) continue;
        const float* rm = spmean + (size_t)n * HW + yy * 128;
        const float* rx = spmax  + (size_t)n * HW + yy * 128;
        #pragma unroll
        for (int dx = -3; dx <= 3; dx++) {
            int xx = x + dx;
            if ((unsigned)xx < 128u) {
                float wm = sw[(dy + 3) * 7 + (dx + 3)];
                float wx = sw[49 + (dy + 3) * 7 + (dx + 3)];
                acc += wm * rm[xx] + wx * rx[xx];
            }
        }
    }
    sa[(size_t)n * HW + y * 128 + x] = sigmoidf_(acc);
}

// ---------------------------------------------------------------- final blend
// 2 float4 per thread: 6 vector loads in flight (ILP), pairs never straddle a
// channel plane since i0 is even and planes are 4096 float4s.
__global__ void k_out(const float4* __restrict__ fvi, const float4* __restrict__ fir,
                      const float* __restrict__ wch, const float* __restrict__ ca,
                      const float4* __restrict__ sa, float4* __restrict__ out) {
    size_t i0 = ((size_t)blockIdx.x * 256 + threadIdx.x) * 2;
    size_t i1 = i0 + 1;
    float4 a0 = fvi[i0], a1 = fvi[i1];
    float4 b0 = fir[i0], b1 = fir[i1];
    int p40 = (int)(i0 & 4095);     // HW/4 - 1
    int nc  = (int)(i0 >> 12);
    int n   = nc >> 7;
    float4 s0 = sa[(size_t)n * 4096 + p40];
    float4 s1 = sa[(size_t)n * 4096 + p40 + 1];
    float u  = wch[nc];
    float cv = ca[nc];
    float4 o0, o1;
    {
        float w = sigmoidf_(s0.x * cv);
        o0.x = w * (b0.x * u + a0.x) + (1.f - w) * (a0.x * u + b0.x);
    }
    {
        float w = sigmoidf_(s0.y * cv);
        o0.y = w * (b0.y * u + a0.y) + (1.f - w) * (a0.y * u + b0.y);
    }
    {
        float w = sigmoidf_(s0.z * cv);
        o0.z = w * (b0.z * u + a0.z) + (1.f - w) * (a0.z * u + b0.z);
    }
    {
        float w = sigmoidf_(s0.w * cv);
        o0.w = w * (b0.w * u + a0.w) + (1.f - w) * (a0.w * u + b0.w);
    }
    {
        float w = sigmoidf_(s1.x * cv);
        o1.x = w * (b1.x * u + a1.x) + (1.f - w) * (a1.x * u + b1.x);
    }
    {
        float w = sigmoidf_(s1.y * cv);
        o1.y = w * (b1.y * u + a1.y) + (1.f - w) * (a1.y * u + b1.y);
    }
    {
        float w = sigmoidf_(s1.z * cv);
        o1.z = w * (b1.z * u + a1.z) + (1.f - w) * (a1.z * u + b1.z);
    }
    {
        float w = sigmoidf_(s1.w * cv);
        o1.w = w * (b1.w * u + a1.w) + (1.f - w) * (a1.w * u + b1.w);
    }
    out[i0] = o0;
    out[i1] = o1;
}

// ----------------------------------------------------------------
extern "C" void kernel_launch(void* const* d_in, const int* in_sizes, int n_in,
                              void* d_out, int out_size, void* d_ws, size_t ws_size,
                              hipStream_t stream) {
    const float* fvi     = (const float*)d_in[0];
    const float* fir     = (const float*)d_in[1];
    const float* ca1_w   = (const float*)d_in[2];
    const float* ca1_b   = (const float*)d_in[3];
    const float* bn_a_g  = (const float*)d_in[4];
    const float* bn_a_b  = (const float*)d_in[5];
    const float* bn_a_m  = (const float*)d_in[6];
    const float* bn_a_v  = (const float*)d_in[7];
    const float* ca2_w   = (const float*)d_in[8];
    const float* ca2_b   = (const float*)d_in[9];
    const float* bn_b_g  = (const float*)d_in[10];
    const float* bn_b_b  = (const float*)d_in[11];
    const float* bn_b_m  = (const float*)d_in[12];
    const float* bn_b_v  = (const float*)d_in[13];
    const float* conv1_w = (const float*)d_in[14];
    const float* conv1_b = (const float*)d_in[15];
    const float* bn_c_g  = (const float*)d_in[16];
    const float* bn_c_b  = (const float*)d_in[17];
    const float* bn_c_m  = (const float*)d_in[18];
    const float* bn_c_v  = (const float*)d_in[19];
    const float* chatt_w1 = (const float*)d_in[20];
    const float* chatt_w2 = (const float*)d_in[21];
    const float* sa_w     = (const float*)d_in[22];

    float* ws = (float*)d_ws;
    float* out = (float*)d_out;

    k_pool<<<NB * C2X, 256, 0, stream>>>(fvi, fir, ws + WS_POOLED);
    k_wch<<<NB, 128, 0, stream>>>(ws + WS_POOLED, ca1_w, ca1_b,
                                  bn_a_g, bn_a_b, bn_a_m, bn_a_v,
                                  ca2_w, ca2_b, bn_b_g, bn_b_b, bn_b_m, bn_b_v,
                                  ws + WS_WCH);
    k_mkweights<<<NB * CCH, 128, 0, stream>>>(ws + WS_WCH, conv1_w,
                                              bn_c_g, bn_c_b, bn_c_m, bn_c_v, conv1_b,
                                              (ushort_t*)(ws + WS_WV), (ushort_t*)(ws + WS_WI),
                                              ws + WS_BC, ws + WS_AVGS);
    k_conv_reduce<<<NB * (HW / 128), 256, 0, stream>>>(fvi, fir,
                                                       (const ushort_t*)(ws + WS_WV),
                                                       (const ushort_t*)(ws + WS_WI),
                                                       ws + WS_BC,
                                                       ws + WS_AVGS, (uint_t*)(ws + WS_MAXB),
                                                       ws + WS_SPMEAN, ws + WS_SPMAX);
    k_ca<<<NB, 128, 0, stream>>>(ws + WS_AVGS, (const uint_t*)(ws + WS_MAXB),
                                 chatt_w1, chatt_w2, ws + WS_CA);
    k_sa<<<NB * 64, 256, 0, stream>>>(ws + WS_SPMEAN, ws + WS_SPMAX, sa_w, ws + WS_SA);
    k_out<<<(NB * CCH * HW / 4) / 512, 256, 0, stream>>>((const float4*)fvi, (const float4*)fir,
                                                         ws + WS_WCH, ws + WS_CA,
                                                         (const float4*)(ws + WS_SA), (float4*)out);
}